// Round 1
// baseline (1224.770 us; speedup 1.0000x reference)
//
#include <hip/hip_runtime.h>
#include <math.h>

#define EPSF 1e-12f

__device__ __forceinline__ float red16(float v) {
    v += __shfl_xor(v, 1, 16);
    v += __shfl_xor(v, 2, 16);
    v += __shfl_xor(v, 4, 16);
    v += __shfl_xor(v, 8, 16);
    return v;
}

// Pass A+B: per-edge attention score -> exp(att), accumulate sum per dst.
// 16 lanes per edge, each lane owns 4 consecutive floats of D=64.
__global__ __launch_bounds__(256) void att_kernel(
    const int* __restrict__ src, const int* __restrict__ dst, const int* __restrict__ etype,
    const float* __restrict__ ent_embed, const float* __restrict__ ent_transfer,
    const float* __restrict__ rel_embed, const float* __restrict__ rel_transfer,
    float* __restrict__ exatt, float* __restrict__ ssum, int E) {
    int gid = blockIdx.x * 256 + threadIdx.x;
    int e = gid >> 4, lane = gid & 15;
    if (e >= E) return;
    int sv = src[e], dv = dst[e], rv = etype[e];
    const float4 te = *(const float4*)(ent_embed    + (size_t)sv * 64 + lane * 4);
    const float4 tp = *(const float4*)(ent_transfer + (size_t)sv * 64 + lane * 4);
    const float4 he = *(const float4*)(ent_embed    + (size_t)dv * 64 + lane * 4);
    const float4 hp = *(const float4*)(ent_transfer + (size_t)dv * 64 + lane * 4);
    const float4 rp = *(const float4*)(rel_transfer + (size_t)rv * 64 + lane * 4);
    const float4 re = *(const float4*)(rel_embed    + (size_t)rv * 64 + lane * 4);

    float dt = te.x*tp.x + te.y*tp.y + te.z*tp.z + te.w*tp.w;
    float dh = he.x*hp.x + he.y*hp.y + he.z*hp.z + he.w*hp.w;
    dt = red16(dt);
    dh = red16(dh);

    float4 mt, mh;
    mt.x = te.x + dt * rp.x; mt.y = te.y + dt * rp.y;
    mt.z = te.z + dt * rp.z; mt.w = te.w + dt * rp.w;
    mh.x = he.x + dh * rp.x; mh.y = he.y + dh * rp.y;
    mh.z = he.z + dh * rp.z; mh.w = he.w + dh * rp.w;

    float sst = mt.x*mt.x + mt.y*mt.y + mt.z*mt.z + mt.w*mt.w;
    float ssh = mh.x*mh.x + mh.y*mh.y + mh.z*mh.z + mh.w*mh.w;
    sst = red16(sst);
    ssh = red16(ssh);
    float it = 1.0f / fmaxf(sqrtf(sst), EPSF);
    float ih = 1.0f / fmaxf(sqrtf(ssh), EPSF);

    float att = mt.x*it * tanhf(mh.x*ih + re.x)
              + mt.y*it * tanhf(mh.y*ih + re.y)
              + mt.z*it * tanhf(mh.z*ih + re.z)
              + mt.w*it * tanhf(mh.w*ih + re.w);
    att = red16(att);

    if (lane == 0) {
        // softmax is shift-invariant; |att| <= 8 so exp() is safe without max-sub
        float ex = expf(att);
        exatt[e] = ex;
        atomicAdd(&ssum[dv], ex);
    }
}

// Pass C: N_h[dst] += (exatt/s[dst]) * node[src], d = 64, 16 lanes/edge
__global__ __launch_bounds__(256) void msg_kernel64(
    const int* __restrict__ src, const int* __restrict__ dst,
    const float* __restrict__ exatt, const float* __restrict__ ssum,
    const float* __restrict__ node, float* __restrict__ Nh, int E) {
    int gid = blockIdx.x * 256 + threadIdx.x;
    int e = gid >> 4, lane = gid & 15;
    if (e >= E) return;
    int dv = dst[e];
    float attn = exatt[e] / fmaxf(ssum[dv], EPSF);
    const float4 v = *(const float4*)(node + (size_t)src[e] * 64 + lane * 4);
    float* p = Nh + (size_t)dv * 64 + lane * 4;
    atomicAdd(p + 0, attn * v.x);
    atomicAdd(p + 1, attn * v.y);
    atomicAdd(p + 2, attn * v.z);
    atomicAdd(p + 3, attn * v.w);
}

// Pass E: same for d = 32, 8 lanes/edge
__global__ __launch_bounds__(256) void msg_kernel32(
    const int* __restrict__ src, const int* __restrict__ dst,
    const float* __restrict__ exatt, const float* __restrict__ ssum,
    const float* __restrict__ node, float* __restrict__ Nh, int E) {
    int gid = blockIdx.x * 256 + threadIdx.x;
    int e = gid >> 3, lane = gid & 7;
    if (e >= E) return;
    int dv = dst[e];
    float attn = exatt[e] / fmaxf(ssum[dv], EPSF);
    const float4 v = *(const float4*)(node + (size_t)src[e] * 32 + lane * 4);
    float* p = Nh + (size_t)dv * 32 + lane * 4;
    atomicAdd(p + 0, attn * v.x);
    atomicAdd(p + 1, attn * v.y);
    atomicAdd(p + 2, attn * v.z);
    atomicAdd(p + 3, attn * v.w);
}

// Pass D: layer-0 bi-interaction update. One wave per node (4 per block).
// out cols 0..63 = ent_embed, 64..95 = l2norm(node1); node1 (raw) -> ws.
__global__ __launch_bounds__(256) void node0_kernel(
    const float* __restrict__ ent_embed, const float* __restrict__ Nh,
    const float* __restrict__ W1, const float* __restrict__ b1,
    const float* __restrict__ W2, const float* __restrict__ b2,
    float* __restrict__ node1, float* __restrict__ out, int N) {
    __shared__ float al[4][64];
    __shared__ float bl[4][64];
    int wave = threadIdx.x >> 6, lane = threadIdx.x & 63;
    int v = blockIdx.x * 4 + wave;
    if (v < N) {
        float e  = ent_embed[(size_t)v * 64 + lane];
        float nh = Nh[(size_t)v * 64 + lane];
        al[wave][lane] = e + nh;
        bl[wave][lane] = e * nh;
        out[(size_t)v * 112 + lane] = e;  // cols 0..63: raw ent_embed
    }
    __syncthreads();
    if (v < N) {
        int j = lane & 31;
        bool second = lane >= 32;
        const float* W  = second ? W2 : W1;
        const float* B  = second ? b2 : b1;
        const float* sl = second ? bl[wave] : al[wave];
        float acc = B[j];
        #pragma unroll
        for (int d = 0; d < 64; d++) acc += sl[d] * W[d * 32 + j];
        acc = acc > 0.0f ? acc : 0.01f * acc;
        float tot = acc + __shfl_xor(acc, 32, 64);  // out1[j] + out2[j]
        float ss = tot * tot;
        ss += __shfl_xor(ss, 1, 32);
        ss += __shfl_xor(ss, 2, 32);
        ss += __shfl_xor(ss, 4, 32);
        ss += __shfl_xor(ss, 8, 32);
        ss += __shfl_xor(ss, 16, 32);
        float inv = 1.0f / fmaxf(sqrtf(ss), EPSF);
        if (!second) {
            node1[(size_t)v * 32 + j] = tot;                 // raw, for layer 1
            out[(size_t)v * 112 + 64 + j] = tot * inv;       // cols 64..95
        }
    }
}

// Pass F: layer-1 update, d=32 -> 16. One wave per node, lanes 0..31 active.
__global__ __launch_bounds__(256) void node1_kernel(
    const float* __restrict__ node1, const float* __restrict__ Nh1,
    const float* __restrict__ W1, const float* __restrict__ b1,
    const float* __restrict__ W2, const float* __restrict__ b2,
    float* __restrict__ out, int N) {
    __shared__ float al[4][32];
    __shared__ float bl[4][32];
    int wave = threadIdx.x >> 6, lane = threadIdx.x & 63;
    int v = blockIdx.x * 4 + wave;
    if (v < N && lane < 32) {
        float n  = node1[(size_t)v * 32 + lane];
        float nh = Nh1[(size_t)v * 32 + lane];
        al[wave][lane] = n + nh;
        bl[wave][lane] = n * nh;
    }
    __syncthreads();
    if (v < N && lane < 32) {
        int j = lane & 15;
        bool second = lane >= 16;
        const float* W  = second ? W2 : W1;
        const float* B  = second ? b2 : b1;
        const float* sl = second ? bl[wave] : al[wave];
        float acc = B[j];
        #pragma unroll
        for (int d = 0; d < 32; d++) acc += sl[d] * W[d * 16 + j];
        acc = acc > 0.0f ? acc : 0.01f * acc;
        float tot = acc + __shfl_xor(acc, 16, 32);
        float ss = tot * tot;
        ss += __shfl_xor(ss, 1, 16);
        ss += __shfl_xor(ss, 2, 16);
        ss += __shfl_xor(ss, 4, 16);
        ss += __shfl_xor(ss, 8, 16);
        float inv = 1.0f / fmaxf(sqrtf(ss), EPSF);
        if (!second) out[(size_t)v * 112 + 96 + j] = tot * inv;  // cols 96..111
    }
}

extern "C" void kernel_launch(void* const* d_in, const int* in_sizes, int n_in,
                              void* d_out, int out_size, void* d_ws, size_t ws_size,
                              hipStream_t stream) {
    const int*   src  = (const int*)d_in[0];
    const int*   dst  = (const int*)d_in[1];
    const int*   ety  = (const int*)d_in[2];
    const float* ent  = (const float*)d_in[3];
    const float* entT = (const float*)d_in[4];
    const float* relE = (const float*)d_in[5];
    const float* relT = (const float*)d_in[6];
    const float* W1_0 = (const float*)d_in[7];
    const float* b1_0 = (const float*)d_in[8];
    const float* W2_0 = (const float*)d_in[9];
    const float* b2_0 = (const float*)d_in[10];
    const float* W1_1 = (const float*)d_in[11];
    const float* b1_1 = (const float*)d_in[12];
    const float* W2_1 = (const float*)d_in[13];
    const float* b2_1 = (const float*)d_in[14];
    float* out = (float*)d_out;

    const int E = in_sizes[0];
    const int N = in_sizes[3] / 64;

    auto al256 = [](size_t x) { return (x + 255) & ~(size_t)255; };
    char* ws = (char*)d_ws;
    size_t offExatt = 0;
    size_t offS     = al256(offExatt + (size_t)E * 4);
    size_t offNh    = al256(offS + (size_t)N * 4);
    size_t offNode1 = al256(offNh + (size_t)N * 64 * 4);
    float* exatt = (float*)(ws + offExatt);
    float* ssum  = (float*)(ws + offS);
    float* Nh0   = (float*)(ws + offNh);      // [N,64]; reused as Nh1 [N,32]
    float* node1 = (float*)(ws + offNode1);   // [N,32]

    hipMemsetAsync(ssum, 0, (size_t)N * 4, stream);
    hipMemsetAsync(Nh0, 0, (size_t)N * 64 * 4, stream);

    int blkA = (E * 16 + 255) / 256;
    att_kernel<<<blkA, 256, 0, stream>>>(src, dst, ety, ent, entT, relE, relT,
                                         exatt, ssum, E);
    msg_kernel64<<<blkA, 256, 0, stream>>>(src, dst, exatt, ssum, ent, Nh0, E);

    int blkN = (N + 3) / 4;
    node0_kernel<<<blkN, 256, 0, stream>>>(ent, Nh0, W1_0, b1_0, W2_0, b2_0,
                                           node1, out, N);

    // reuse Nh0's space as Nh1 [N,32]
    hipMemsetAsync(Nh0, 0, (size_t)N * 32 * 4, stream);
    int blkE32 = (E * 8 + 255) / 256;
    msg_kernel32<<<blkE32, 256, 0, stream>>>(src, dst, exatt, ssum, node1, Nh0, E);

    node1_kernel<<<blkN, 256, 0, stream>>>(node1, Nh0, W1_1, b1_1, W2_1, b2_1,
                                           out, N);
}

// Round 2
// 431.723 us; speedup vs baseline: 2.8369x; 2.8369x over previous
//
#include <hip/hip_runtime.h>
#include <math.h>

#define EPSF 1e-12f

__device__ __forceinline__ float red16(float v) {
    v += __shfl_xor(v, 1, 16);
    v += __shfl_xor(v, 2, 16);
    v += __shfl_xor(v, 4, 16);
    v += __shfl_xor(v, 8, 16);
    return v;
}

// ---------------- CSR build (counting sort by dst) ----------------

__global__ __launch_bounds__(256) void count_deg(
    const int* __restrict__ dst, int* __restrict__ deg, int E) {
    int e = blockIdx.x * 256 + threadIdx.x;
    if (e < E) atomicAdd(&deg[dst[e]], 1);
}

__global__ __launch_bounds__(256) void scan_reduce(
    const int* __restrict__ deg, int* __restrict__ part, int N) {
    __shared__ int sh[256];
    int t = threadIdx.x, i = blockIdx.x * 256 + t;
    sh[t] = (i < N) ? deg[i] : 0;
    __syncthreads();
    for (int off = 128; off > 0; off >>= 1) {
        if (t < off) sh[t] += sh[t + off];
        __syncthreads();
    }
    if (t == 0) part[blockIdx.x] = sh[0];
}

__global__ __launch_bounds__(1024) void scan_part(int* __restrict__ part, int nb) {
    __shared__ int sh[1024];
    int t = threadIdx.x;
    int x = (t < nb) ? part[t] : 0;
    sh[t] = x;
    __syncthreads();
    for (int off = 1; off < 1024; off <<= 1) {
        int y = (t >= off) ? sh[t - off] : 0;
        __syncthreads();
        sh[t] += y;
        __syncthreads();
    }
    if (t < nb) part[t] = sh[t] - x;  // exclusive
}

__global__ __launch_bounds__(256) void scan_write(
    int* __restrict__ rowptr, const int* __restrict__ part, int N) {
    __shared__ int sh[256];
    int t = threadIdx.x, i = blockIdx.x * 256 + t;
    int x = (i < N) ? rowptr[i] : 0;
    sh[t] = x;
    __syncthreads();
    for (int off = 1; off < 256; off <<= 1) {
        int y = (t >= off) ? sh[t - off] : 0;
        __syncthreads();
        sh[t] += y;
        __syncthreads();
    }
    if (i < N) rowptr[i] = part[blockIdx.x] + sh[t] - x;  // exclusive scan
}

// After this, rowptr[v] = end(v); start(v) = (v ? rowptr[v-1] : 0)
__global__ __launch_bounds__(256) void scatter_edges(
    const int* __restrict__ dst, int* __restrict__ rowptr,
    int* __restrict__ eid, int E) {
    int e = blockIdx.x * 256 + threadIdx.x;
    if (e < E) {
        int slot = atomicAdd(&rowptr[dst[e]], 1);
        eid[slot] = e;
    }
}

// ---------------- attention ----------------
// 16 lanes per edge, each lane owns 4 consecutive floats of D=64.
__global__ __launch_bounds__(256) void att_kernel(
    const int* __restrict__ src, const int* __restrict__ dst, const int* __restrict__ etype,
    const float* __restrict__ ent_embed, const float* __restrict__ ent_transfer,
    const float* __restrict__ rel_embed, const float* __restrict__ rel_transfer,
    float* __restrict__ exatt, int E) {
    int gid = blockIdx.x * 256 + threadIdx.x;
    int e = gid >> 4, lane = gid & 15;
    if (e >= E) return;
    int sv = src[e], dv = dst[e], rv = etype[e];
    const float4 te = *(const float4*)(ent_embed    + (size_t)sv * 64 + lane * 4);
    const float4 tp = *(const float4*)(ent_transfer + (size_t)sv * 64 + lane * 4);
    const float4 he = *(const float4*)(ent_embed    + (size_t)dv * 64 + lane * 4);
    const float4 hp = *(const float4*)(ent_transfer + (size_t)dv * 64 + lane * 4);
    const float4 rp = *(const float4*)(rel_transfer + (size_t)rv * 64 + lane * 4);
    const float4 re = *(const float4*)(rel_embed    + (size_t)rv * 64 + lane * 4);

    float dt = te.x*tp.x + te.y*tp.y + te.z*tp.z + te.w*tp.w;
    float dh = he.x*hp.x + he.y*hp.y + he.z*hp.z + he.w*hp.w;
    dt = red16(dt);
    dh = red16(dh);

    float4 mt, mh;
    mt.x = te.x + dt * rp.x; mt.y = te.y + dt * rp.y;
    mt.z = te.z + dt * rp.z; mt.w = te.w + dt * rp.w;
    mh.x = he.x + dh * rp.x; mh.y = he.y + dh * rp.y;
    mh.z = he.z + dh * rp.z; mh.w = he.w + dh * rp.w;

    float sst = mt.x*mt.x + mt.y*mt.y + mt.z*mt.z + mt.w*mt.w;
    float ssh = mh.x*mh.x + mh.y*mh.y + mh.z*mh.z + mh.w*mh.w;
    sst = red16(sst);
    ssh = red16(ssh);
    float it = 1.0f / fmaxf(sqrtf(sst), EPSF);
    float ih = 1.0f / fmaxf(sqrtf(ssh), EPSF);

    float att = mt.x*it * tanhf(mh.x*ih + re.x)
              + mt.y*it * tanhf(mh.y*ih + re.y)
              + mt.z*it * tanhf(mh.z*ih + re.z)
              + mt.w*it * tanhf(mh.w*ih + re.w);
    att = red16(att);

    // softmax is shift-invariant; |att| <= 8 so exp() is safe without max-sub
    if (lane == 0) exatt[e] = expf(att);
}

// per-dst sum of exp(att); one thread per node over its CSR range
__global__ __launch_bounds__(256) void ssum_kernel(
    const int* __restrict__ rowptr, const int* __restrict__ eid,
    const float* __restrict__ exatt, float* __restrict__ ssum, int N) {
    int v = blockIdx.x * 256 + threadIdx.x;
    if (v >= N) return;
    int s = v ? rowptr[v - 1] : 0;
    int epos = rowptr[v];
    float acc = 0.0f;
    for (int i = s; i < epos; i++) acc += exatt[eid[i]];
    ssum[v] = acc;
}

// exatt[e] -> exatt[e] / max(ssum[dst[e]], eps)   (in place)
__global__ __launch_bounds__(256) void norm_att(
    const int* __restrict__ dst, const float* __restrict__ ssum,
    float* __restrict__ exatt, int E) {
    int e = blockIdx.x * 256 + threadIdx.x;
    if (e < E) exatt[e] = exatt[e] / fmaxf(ssum[dst[e]], EPSF);
}

// ---------------- message gathers (no atomics) ----------------
// d=64: 16 lanes per dst node, each lane owns a float4 of dims
__global__ __launch_bounds__(256) void gmsg64(
    const int* __restrict__ rowptr, const int* __restrict__ eid,
    const int* __restrict__ src, const float* __restrict__ att,
    const float* __restrict__ node, float* __restrict__ Nh, int N) {
    int gid = blockIdx.x * 256 + threadIdx.x;
    int v = gid >> 4, lane = gid & 15;
    if (v >= N) return;
    int s = v ? rowptr[v - 1] : 0;
    int epos = rowptr[v];
    float4 acc = {0.f, 0.f, 0.f, 0.f};
    for (int i = s; i < epos; i++) {
        int e = eid[i];
        float a = att[e];
        const float4 x = *(const float4*)(node + (size_t)src[e] * 64 + lane * 4);
        acc.x += a * x.x; acc.y += a * x.y; acc.z += a * x.z; acc.w += a * x.w;
    }
    *(float4*)(Nh + (size_t)v * 64 + lane * 4) = acc;
}

// d=32 (node1 lives in out[], row stride 112, col offset 64): 8 lanes per node
__global__ __launch_bounds__(256) void gmsg32(
    const int* __restrict__ rowptr, const int* __restrict__ eid,
    const int* __restrict__ src, const float* __restrict__ att,
    const float* __restrict__ out, float* __restrict__ Nh, int N) {
    int gid = blockIdx.x * 256 + threadIdx.x;
    int v = gid >> 3, lane = gid & 7;
    if (v >= N) return;
    int s = v ? rowptr[v - 1] : 0;
    int epos = rowptr[v];
    float4 acc = {0.f, 0.f, 0.f, 0.f};
    for (int i = s; i < epos; i++) {
        int e = eid[i];
        float a = att[e];
        const float4 x = *(const float4*)(out + (size_t)src[e] * 112 + 64 + lane * 4);
        acc.x += a * x.x; acc.y += a * x.y; acc.z += a * x.z; acc.w += a * x.w;
    }
    *(float4*)(Nh + (size_t)v * 32 + lane * 4) = acc;
}

// ---------------- node updates ----------------
// Layer 0: one wave per node (4/block). Writes out cols 0..63 (= ent_embed)
// and cols 64..95 = RAW node1 (normalized later by node1_kernel).
__global__ __launch_bounds__(256) void node0_kernel(
    const float* __restrict__ ent_embed, const float* __restrict__ Nh,
    const float* __restrict__ W1, const float* __restrict__ b1,
    const float* __restrict__ W2, const float* __restrict__ b2,
    float* __restrict__ out, int N) {
    __shared__ float al[4][64];
    __shared__ float bl[4][64];
    int wave = threadIdx.x >> 6, lane = threadIdx.x & 63;
    int v = blockIdx.x * 4 + wave;
    if (v < N) {
        float e  = ent_embed[(size_t)v * 64 + lane];
        float nh = Nh[(size_t)v * 64 + lane];
        al[wave][lane] = e + nh;
        bl[wave][lane] = e * nh;
        out[(size_t)v * 112 + lane] = e;  // cols 0..63
    }
    __syncthreads();
    if (v < N) {
        int j = lane & 31;
        bool second = lane >= 32;
        const float* W  = second ? W2 : W1;
        const float* B  = second ? b2 : b1;
        const float* sl = second ? bl[wave] : al[wave];
        float acc = B[j];
        #pragma unroll
        for (int d = 0; d < 64; d++) acc += sl[d] * W[d * 32 + j];
        acc = acc > 0.0f ? acc : 0.01f * acc;
        float tot = acc + __shfl_xor(acc, 32, 64);  // out1[j] + out2[j]
        if (!second) out[(size_t)v * 112 + 64 + j] = tot;  // raw node1
    }
}

// Layer 1: reads raw node1 from out cols 64..95 + Nh1; writes normalized
// node1 back to cols 64..95 and final layer to cols 96..111.
__global__ __launch_bounds__(256) void node1_kernel(
    const float* __restrict__ Nh1,
    const float* __restrict__ W1, const float* __restrict__ b1,
    const float* __restrict__ W2, const float* __restrict__ b2,
    float* __restrict__ out, int N) {
    __shared__ float al[4][32];
    __shared__ float bl[4][32];
    int wave = threadIdx.x >> 6, lane = threadIdx.x & 63;
    int v = blockIdx.x * 4 + wave;
    float n = 0.0f;
    if (v < N && lane < 32) {
        n = out[(size_t)v * 112 + 64 + lane];
        float nh = Nh1[(size_t)v * 32 + lane];
        al[wave][lane] = n + nh;
        bl[wave][lane] = n * nh;
    }
    __syncthreads();
    if (v < N && lane < 32) {
        // l2-normalize node1 -> out cols 64..95
        float ss = n * n;
        ss += __shfl_xor(ss, 1, 32);
        ss += __shfl_xor(ss, 2, 32);
        ss += __shfl_xor(ss, 4, 32);
        ss += __shfl_xor(ss, 8, 32);
        ss += __shfl_xor(ss, 16, 32);
        float inv1 = 1.0f / fmaxf(sqrtf(ss), EPSF);
        out[(size_t)v * 112 + 64 + lane] = n * inv1;

        int j = lane & 15;
        bool second = lane >= 16;
        const float* W  = second ? W2 : W1;
        const float* B  = second ? b2 : b1;
        const float* sl = second ? bl[wave] : al[wave];
        float acc = B[j];
        #pragma unroll
        for (int d = 0; d < 32; d++) acc += sl[d] * W[d * 16 + j];
        acc = acc > 0.0f ? acc : 0.01f * acc;
        float tot = acc + __shfl_xor(acc, 16, 32);
        float s2 = tot * tot;
        s2 += __shfl_xor(s2, 1, 16);
        s2 += __shfl_xor(s2, 2, 16);
        s2 += __shfl_xor(s2, 4, 16);
        s2 += __shfl_xor(s2, 8, 16);
        float inv2 = 1.0f / fmaxf(sqrtf(s2), EPSF);
        if (!second) out[(size_t)v * 112 + 96 + j] = tot * inv2;  // cols 96..111
    }
}

extern "C" void kernel_launch(void* const* d_in, const int* in_sizes, int n_in,
                              void* d_out, int out_size, void* d_ws, size_t ws_size,
                              hipStream_t stream) {
    const int*   src  = (const int*)d_in[0];
    const int*   dst  = (const int*)d_in[1];
    const int*   ety  = (const int*)d_in[2];
    const float* ent  = (const float*)d_in[3];
    const float* entT = (const float*)d_in[4];
    const float* relE = (const float*)d_in[5];
    const float* relT = (const float*)d_in[6];
    const float* W1_0 = (const float*)d_in[7];
    const float* b1_0 = (const float*)d_in[8];
    const float* W2_0 = (const float*)d_in[9];
    const float* b2_0 = (const float*)d_in[10];
    const float* W1_1 = (const float*)d_in[11];
    const float* b1_1 = (const float*)d_in[12];
    const float* W2_1 = (const float*)d_in[13];
    const float* b2_1 = (const float*)d_in[14];
    float* out = (float*)d_out;

    const int E = in_sizes[0];
    const int N = in_sizes[3] / 64;
    const int nb = (N + 255) / 256;  // scan blocks (<=1024 required)

    auto al256 = [](size_t x) { return (x + 255) & ~(size_t)255; };
    char* ws = (char*)d_ws;
    size_t offExatt = 0;
    size_t offS     = al256(offExatt + (size_t)E * 4);
    size_t offNh    = al256(offS + (size_t)N * 4);
    size_t offRow   = al256(offNh + (size_t)N * 64 * 4);
    size_t offEid   = al256(offRow + (size_t)N * 4);
    size_t offPart  = al256(offEid + (size_t)E * 4);
    float* exatt  = (float*)(ws + offExatt);
    float* ssum   = (float*)(ws + offS);
    float* Nh0    = (float*)(ws + offNh);    // [N,64]; reused as Nh1 [N,32]
    int*   rowptr = (int*)(ws + offRow);
    int*   eid    = (int*)(ws + offEid);
    int*   part   = (int*)(ws + offPart);

    // ---- CSR build ----
    hipMemsetAsync(rowptr, 0, (size_t)N * 4, stream);
    int blkE = (E + 255) / 256;
    count_deg<<<blkE, 256, 0, stream>>>(dst, rowptr, E);
    scan_reduce<<<nb, 256, 0, stream>>>(rowptr, part, N);
    scan_part<<<1, 1024, 0, stream>>>(part, nb);
    scan_write<<<nb, 256, 0, stream>>>(rowptr, part, N);
    scatter_edges<<<blkE, 256, 0, stream>>>(dst, rowptr, eid, E);

    // ---- attention + edge softmax ----
    int blkA = (E * 16 + 255) / 256;
    att_kernel<<<blkA, 256, 0, stream>>>(src, dst, ety, ent, entT, relE, relT,
                                         exatt, E);
    ssum_kernel<<<nb, 256, 0, stream>>>(rowptr, eid, exatt, ssum, N);
    norm_att<<<blkE, 256, 0, stream>>>(dst, ssum, exatt, E);

    // ---- layer 0 ----
    gmsg64<<<(N * 16 + 255) / 256, 256, 0, stream>>>(rowptr, eid, src, exatt,
                                                     ent, Nh0, N);
    int blkN = (N + 3) / 4;
    node0_kernel<<<blkN, 256, 0, stream>>>(ent, Nh0, W1_0, b1_0, W2_0, b2_0,
                                           out, N);

    // ---- layer 1 (node1 lives in out cols 64..95, raw) ----
    gmsg32<<<(N * 8 + 255) / 256, 256, 0, stream>>>(rowptr, eid, src, exatt,
                                                    out, Nh0, N);
    node1_kernel<<<blkN, 256, 0, stream>>>(Nh0, W1_1, b1_1, W2_1, b2_1, out, N);
}

// Round 3
// 315.855 us; speedup vs baseline: 3.8776x; 1.3668x over previous
//
#include <hip/hip_runtime.h>
#include <math.h>

#define EPSF 1e-12f

__device__ __forceinline__ float red16(float v) {
    v += __shfl_xor(v, 1, 16);
    v += __shfl_xor(v, 2, 16);
    v += __shfl_xor(v, 4, 16);
    v += __shfl_xor(v, 8, 16);
    return v;
}

// branch-free tanh via hardware exp; exact at +/-inf limits
__device__ __forceinline__ float fast_tanh(float x) {
    return 1.0f - 2.0f / (__expf(2.0f * x) + 1.0f);
}

// ---------------- CSR build (counting sort by dst) ----------------

__global__ __launch_bounds__(256) void count_deg(
    const int* __restrict__ dst, int* __restrict__ deg, int E) {
    int e = blockIdx.x * 256 + threadIdx.x;
    if (e < E) atomicAdd(&deg[dst[e]], 1);
}

__global__ __launch_bounds__(256) void scan_reduce(
    const int* __restrict__ deg, int* __restrict__ part, int N) {
    __shared__ int sh[256];
    int t = threadIdx.x, i = blockIdx.x * 256 + t;
    sh[t] = (i < N) ? deg[i] : 0;
    __syncthreads();
    for (int off = 128; off > 0; off >>= 1) {
        if (t < off) sh[t] += sh[t + off];
        __syncthreads();
    }
    if (t == 0) part[blockIdx.x] = sh[0];
}

__global__ __launch_bounds__(1024) void scan_part(int* __restrict__ part, int nb) {
    __shared__ int sh[1024];
    int t = threadIdx.x;
    int x = (t < nb) ? part[t] : 0;
    sh[t] = x;
    __syncthreads();
    for (int off = 1; off < 1024; off <<= 1) {
        int y = (t >= off) ? sh[t - off] : 0;
        __syncthreads();
        sh[t] += y;
        __syncthreads();
    }
    if (t < nb) part[t] = sh[t] - x;  // exclusive
}

__global__ __launch_bounds__(256) void scan_write(
    int* __restrict__ rowptr, const int* __restrict__ part, int N) {
    __shared__ int sh[256];
    int t = threadIdx.x, i = blockIdx.x * 256 + t;
    int x = (i < N) ? rowptr[i] : 0;
    sh[t] = x;
    __syncthreads();
    for (int off = 1; off < 256; off <<= 1) {
        int y = (t >= off) ? sh[t - off] : 0;
        __syncthreads();
        sh[t] += y;
        __syncthreads();
    }
    if (i < N) rowptr[i] = part[blockIdx.x] + sh[t] - x;  // exclusive scan
}

// After this, rowptr[v] = end(v); start(v) = (v ? rowptr[v-1] : 0).
// Sorts src/etype into CSR slot order (removes indirection later).
__global__ __launch_bounds__(256) void scatter_edges(
    const int* __restrict__ src, const int* __restrict__ dst,
    const int* __restrict__ ety, int* __restrict__ rowptr,
    int* __restrict__ ssrc, int* __restrict__ sety, int E) {
    int e = blockIdx.x * 256 + threadIdx.x;
    if (e < E) {
        int slot = atomicAdd(&rowptr[dst[e]], 1);
        ssrc[slot] = src[e];
        sety[slot] = ety[e];
    }
}

// ---------------- fused layer-0: att + edge-softmax + message ----------------
// 16 lanes per dst node; each lane owns 4 consecutive dims of D=64.
// Per edge: ex = exp(att). Stores raw ex per CSR slot, 1/sum(ex) per node,
// and Nh[v] = (sum ex_e * ent[src_e]) / sum(ex) computed fully in registers.
__global__ __launch_bounds__(256) void fused_l0(
    const int* __restrict__ rowptr, const int* __restrict__ ssrc,
    const int* __restrict__ sety,
    const float* __restrict__ ent, const float* __restrict__ entT,
    const float* __restrict__ relE, const float* __restrict__ relT,
    float* __restrict__ exatt, float* __restrict__ sinv,
    float* __restrict__ Nh, int N) {
    int gid = blockIdx.x * 256 + threadIdx.x;
    int v = gid >> 4, lane = gid & 15;
    if (v >= N) return;
    int s = v ? rowptr[v - 1] : 0;
    int epos = rowptr[v];

    const float4 he = *(const float4*)(ent  + (size_t)v * 64 + lane * 4);
    const float4 hp = *(const float4*)(entT + (size_t)v * 64 + lane * 4);
    float dh = red16(he.x*hp.x + he.y*hp.y + he.z*hp.z + he.w*hp.w);

    float4 macc = {0.f, 0.f, 0.f, 0.f};
    float sumex = 0.0f;

    for (int i = s; i < epos; ++i) {
        int sv = ssrc[i], rv = sety[i];
        const float4 te = *(const float4*)(ent  + (size_t)sv * 64 + lane * 4);
        const float4 tp = *(const float4*)(entT + (size_t)sv * 64 + lane * 4);
        const float4 rp = *(const float4*)(relT + (size_t)rv * 64 + lane * 4);
        const float4 re = *(const float4*)(relE + (size_t)rv * 64 + lane * 4);

        float dt = red16(te.x*tp.x + te.y*tp.y + te.z*tp.z + te.w*tp.w);

        float4 mt, mh;
        mt.x = te.x + dt * rp.x; mt.y = te.y + dt * rp.y;
        mt.z = te.z + dt * rp.z; mt.w = te.w + dt * rp.w;
        mh.x = he.x + dh * rp.x; mh.y = he.y + dh * rp.y;
        mh.z = he.z + dh * rp.z; mh.w = he.w + dh * rp.w;

        float sst = red16(mt.x*mt.x + mt.y*mt.y + mt.z*mt.z + mt.w*mt.w);
        float ssh = red16(mh.x*mh.x + mh.y*mh.y + mh.z*mh.z + mh.w*mh.w);
        float it = 1.0f / fmaxf(sqrtf(sst), EPSF);
        float ih = 1.0f / fmaxf(sqrtf(ssh), EPSF);

        float att = red16(mt.x*it * fast_tanh(mh.x*ih + re.x)
                        + mt.y*it * fast_tanh(mh.y*ih + re.y)
                        + mt.z*it * fast_tanh(mh.z*ih + re.z)
                        + mt.w*it * fast_tanh(mh.w*ih + re.w));
        // softmax shift-invariant; |att| <= 8 so exp is safe without max-sub
        float ex = __expf(att);                 // identical across all 16 lanes
        if (lane == 0) exatt[i] = ex;           // raw; consumers scale by sinv
        sumex += ex;
        macc.x += ex * te.x; macc.y += ex * te.y;
        macc.z += ex * te.z; macc.w += ex * te.w;
    }

    float inv = 1.0f / fmaxf(sumex, EPSF);
    if (lane == 0) sinv[v] = inv;
    macc.x *= inv; macc.y *= inv; macc.z *= inv; macc.w *= inv;
    *(float4*)(Nh + (size_t)v * 64 + lane * 4) = macc;
}

// ---------------- layer-1 message gather (no atomics) ----------------
// node1 (raw) lives in out[] cols 64..95, row stride 112. 8 lanes per node.
__global__ __launch_bounds__(256) void gmsg32(
    const int* __restrict__ rowptr, const int* __restrict__ ssrc,
    const float* __restrict__ exatt, const float* __restrict__ sinv,
    const float* __restrict__ out, float* __restrict__ Nh, int N) {
    int gid = blockIdx.x * 256 + threadIdx.x;
    int v = gid >> 3, lane = gid & 7;
    if (v >= N) return;
    int s = v ? rowptr[v - 1] : 0;
    int epos = rowptr[v];
    float4 acc = {0.f, 0.f, 0.f, 0.f};
    for (int i = s; i < epos; ++i) {
        float a = exatt[i];
        const float4 x = *(const float4*)(out + (size_t)ssrc[i] * 112 + 64 + lane * 4);
        acc.x += a * x.x; acc.y += a * x.y; acc.z += a * x.z; acc.w += a * x.w;
    }
    float inv = sinv[v];
    acc.x *= inv; acc.y *= inv; acc.z *= inv; acc.w *= inv;
    *(float4*)(Nh + (size_t)v * 32 + lane * 4) = acc;
}

// ---------------- node updates ----------------
// Layer 0: one wave per node (4/block). Writes out cols 0..63 (= ent_embed)
// and cols 64..95 = RAW node1 (normalized later by node1_kernel).
__global__ __launch_bounds__(256) void node0_kernel(
    const float* __restrict__ ent_embed, const float* __restrict__ Nh,
    const float* __restrict__ W1, const float* __restrict__ b1,
    const float* __restrict__ W2, const float* __restrict__ b2,
    float* __restrict__ out, int N) {
    __shared__ float al[4][64];
    __shared__ float bl[4][64];
    int wave = threadIdx.x >> 6, lane = threadIdx.x & 63;
    int v = blockIdx.x * 4 + wave;
    if (v < N) {
        float e  = ent_embed[(size_t)v * 64 + lane];
        float nh = Nh[(size_t)v * 64 + lane];
        al[wave][lane] = e + nh;
        bl[wave][lane] = e * nh;
        out[(size_t)v * 112 + lane] = e;  // cols 0..63
    }
    __syncthreads();
    if (v < N) {
        int j = lane & 31;
        bool second = lane >= 32;
        const float* W  = second ? W2 : W1;
        const float* B  = second ? b2 : b1;
        const float* sl = second ? bl[wave] : al[wave];
        float acc = B[j];
        #pragma unroll
        for (int d = 0; d < 64; d++) acc += sl[d] * W[d * 32 + j];
        acc = acc > 0.0f ? acc : 0.01f * acc;
        float tot = acc + __shfl_xor(acc, 32, 64);  // out1[j] + out2[j]
        if (!second) out[(size_t)v * 112 + 64 + j] = tot;  // raw node1
    }
}

// Layer 1: reads raw node1 from out cols 64..95 + Nh1; writes normalized
// node1 back to cols 64..95 and final layer to cols 96..111.
__global__ __launch_bounds__(256) void node1_kernel(
    const float* __restrict__ Nh1,
    const float* __restrict__ W1, const float* __restrict__ b1,
    const float* __restrict__ W2, const float* __restrict__ b2,
    float* __restrict__ out, int N) {
    __shared__ float al[4][32];
    __shared__ float bl[4][32];
    int wave = threadIdx.x >> 6, lane = threadIdx.x & 63;
    int v = blockIdx.x * 4 + wave;
    float n = 0.0f;
    if (v < N && lane < 32) {
        n = out[(size_t)v * 112 + 64 + lane];
        float nh = Nh1[(size_t)v * 32 + lane];
        al[wave][lane] = n + nh;
        bl[wave][lane] = n * nh;
    }
    __syncthreads();
    if (v < N && lane < 32) {
        // l2-normalize node1 -> out cols 64..95
        float ss = n * n;
        ss += __shfl_xor(ss, 1, 32);
        ss += __shfl_xor(ss, 2, 32);
        ss += __shfl_xor(ss, 4, 32);
        ss += __shfl_xor(ss, 8, 32);
        ss += __shfl_xor(ss, 16, 32);
        float inv1 = 1.0f / fmaxf(sqrtf(ss), EPSF);
        out[(size_t)v * 112 + 64 + lane] = n * inv1;

        int j = lane & 15;
        bool second = lane >= 16;
        const float* W  = second ? W2 : W1;
        const float* B  = second ? b2 : b1;
        const float* sl = second ? bl[wave] : al[wave];
        float acc = B[j];
        #pragma unroll
        for (int d = 0; d < 32; d++) acc += sl[d] * W[d * 16 + j];
        acc = acc > 0.0f ? acc : 0.01f * acc;
        float tot = acc + __shfl_xor(acc, 16, 32);
        float s2 = tot * tot;
        s2 += __shfl_xor(s2, 1, 16);
        s2 += __shfl_xor(s2, 2, 16);
        s2 += __shfl_xor(s2, 4, 16);
        s2 += __shfl_xor(s2, 8, 16);
        float inv2 = 1.0f / fmaxf(sqrtf(s2), EPSF);
        if (!second) out[(size_t)v * 112 + 96 + j] = tot * inv2;  // cols 96..111
    }
}

extern "C" void kernel_launch(void* const* d_in, const int* in_sizes, int n_in,
                              void* d_out, int out_size, void* d_ws, size_t ws_size,
                              hipStream_t stream) {
    const int*   src  = (const int*)d_in[0];
    const int*   dst  = (const int*)d_in[1];
    const int*   ety  = (const int*)d_in[2];
    const float* ent  = (const float*)d_in[3];
    const float* entT = (const float*)d_in[4];
    const float* relE = (const float*)d_in[5];
    const float* relT = (const float*)d_in[6];
    const float* W1_0 = (const float*)d_in[7];
    const float* b1_0 = (const float*)d_in[8];
    const float* W2_0 = (const float*)d_in[9];
    const float* b2_0 = (const float*)d_in[10];
    const float* W1_1 = (const float*)d_in[11];
    const float* b1_1 = (const float*)d_in[12];
    const float* W2_1 = (const float*)d_in[13];
    const float* b2_1 = (const float*)d_in[14];
    float* out = (float*)d_out;

    const int E = in_sizes[0];
    const int N = in_sizes[3] / 64;
    const int nb = (N + 255) / 256;  // scan blocks (must be <= 1024)

    auto al256 = [](size_t x) { return (x + 255) & ~(size_t)255; };
    char* ws = (char*)d_ws;
    size_t offExatt = 0;
    size_t offS     = al256(offExatt + (size_t)E * 4);
    size_t offNh    = al256(offS + (size_t)N * 4);
    size_t offRow   = al256(offNh + (size_t)N * 64 * 4);
    size_t offSsrc  = al256(offRow + (size_t)N * 4);
    size_t offSety  = al256(offSsrc + (size_t)E * 4);
    size_t offPart  = al256(offSety + (size_t)E * 4);
    float* exatt  = (float*)(ws + offExatt);
    float* sinv   = (float*)(ws + offS);
    float* Nh0    = (float*)(ws + offNh);    // [N,64]; reused as Nh1 [N,32]
    int*   rowptr = (int*)(ws + offRow);
    int*   ssrc   = (int*)(ws + offSsrc);
    int*   sety   = (int*)(ws + offSety);
    int*   part   = (int*)(ws + offPart);

    // ---- CSR build ----
    hipMemsetAsync(rowptr, 0, (size_t)N * 4, stream);
    int blkE = (E + 255) / 256;
    count_deg<<<blkE, 256, 0, stream>>>(dst, rowptr, E);
    scan_reduce<<<nb, 256, 0, stream>>>(rowptr, part, N);
    scan_part<<<1, 1024, 0, stream>>>(part, nb);
    scan_write<<<nb, 256, 0, stream>>>(rowptr, part, N);
    scatter_edges<<<blkE, 256, 0, stream>>>(src, dst, ety, rowptr, ssrc, sety, E);

    // ---- fused layer-0: attention + softmax + message ----
    fused_l0<<<(N * 16 + 255) / 256, 256, 0, stream>>>(
        rowptr, ssrc, sety, ent, entT, relE, relT, exatt, sinv, Nh0, N);

    int blkN = (N + 3) / 4;
    node0_kernel<<<blkN, 256, 0, stream>>>(ent, Nh0, W1_0, b1_0, W2_0, b2_0,
                                           out, N);

    // ---- layer 1 (node1 lives in out cols 64..95, raw) ----
    gmsg32<<<(N * 8 + 255) / 256, 256, 0, stream>>>(rowptr, ssrc, exatt, sinv,
                                                    out, Nh0, N);
    node1_kernel<<<blkN, 256, 0, stream>>>(Nh0, W1_1, b1_1, W2_1, b2_1, out, N);
}